// Round 1
// baseline (413.502 us; speedup 1.0000x reference)
//
#include <hip/hip_runtime.h>

typedef unsigned int u32;
typedef unsigned short u16;
typedef u16 u16x4 __attribute__((ext_vector_type(4)));
typedef u16 u16x8 __attribute__((ext_vector_type(8)));
typedef __bf16 bf16x8 __attribute__((ext_vector_type(8)));
typedef float f32x4 __attribute__((ext_vector_type(4)));

#define LDK 136   // padded LDS leading dim (elems): 16B-aligned rows
#define MFMA(a, b, c) __builtin_amdgcn_mfma_f32_16x16x32_bf16(a, b, c, 0, 0, 0)

__device__ __forceinline__ u16 f2b(float f) {
  u32 u = __builtin_bit_cast(u32, f);
  u = (u + 0x7fffu + ((u >> 16) & 1u)) >> 16;
  return (u16)u;
}
__device__ __forceinline__ float b2f(u16 h) {
  u32 u = ((u32)h) << 16;
  return __builtin_bit_cast(float, u);
}

// ---------------- weight prep: wT[m][d][c] = bf16(W_m[c][d]) ----------------
__global__ void wprep(const float* __restrict__ Wq, const float* __restrict__ Wk,
                      const float* __restrict__ Wv, const float* __restrict__ Ws,
                      u16* __restrict__ wT) {
  const float* srcs[4] = {Wq, Wk, Wv, Ws};
  const float* s = srcs[blockIdx.x];
  u16* d = wT + (size_t)blockIdx.x * 16384;
  for (int idx = threadIdx.x; idx < 16384; idx += 256) {
    int i = idx >> 7, j = idx & 127;   // W[i=c_in][j=c_out]
    d[j * 128 + i] = f2b(s[idx]);
  }
}

// stage x row-tile -> Xs[w][c] bf16
__device__ __forceinline__ void stage_x(u16* __restrict__ Xs,
                                        const float* __restrict__ xin,
                                        size_t pixbase, int t) {
#pragma unroll
  for (int j = 0; j < 8; ++j) {
    int lin = j * 256 + t;
    int w = lin >> 4, c0 = (lin & 15) << 3;
    f32x4 a0 = *(const f32x4*)&xin[pixbase + lin * 8];
    f32x4 a1 = *(const f32x4*)&xin[pixbase + lin * 8 + 4];
    u16x8 p;
#pragma unroll
    for (int i = 0; i < 4; ++i) { p[i] = f2b(a0[i]); p[4 + i] = f2b(a1[i]); }
    *(u16x8*)&Xs[w * LDK + c0] = p;
  }
}

// 128x128x128 GEMM vs transposed weight, ReLU, transposed store [c][w]
__device__ __forceinline__ void gemm_relu_store(const u16* __restrict__ Xs,
                                                const u16* __restrict__ wb,
                                                u16* __restrict__ dst, size_t obase,
                                                int lrow, int lq, int nstrip) {
  bf16x8 w0[4], w1[4];
#pragma unroll
  for (int kk = 0; kk < 4; ++kk) {
    int ko = kk * 32 + lq * 8;
    w0[kk] = *(const bf16x8*)&wb[(nstrip + lrow) * 128 + ko];
    w1[kk] = *(const bf16x8*)&wb[(nstrip + 16 + lrow) * 128 + ko];
  }
  f32x4 acc[8][2];
#pragma unroll
  for (int mt = 0; mt < 8; ++mt) {
    acc[mt][0] = (f32x4){0.f, 0.f, 0.f, 0.f};
    acc[mt][1] = (f32x4){0.f, 0.f, 0.f, 0.f};
  }
#pragma unroll
  for (int kk = 0; kk < 4; ++kk) {
    int ko = kk * 32 + lq * 8;
#pragma unroll
    for (int mt = 0; mt < 8; ++mt) {
      bf16x8 a = *(const bf16x8*)&Xs[(mt * 16 + lrow) * LDK + ko];
      acc[mt][0] = MFMA(a, w0[kk], acc[mt][0]);
      acc[mt][1] = MFMA(a, w1[kk], acc[mt][1]);
    }
  }
#pragma unroll
  for (int mt = 0; mt < 8; ++mt) {
    int w0i = mt * 16 + lq * 4;
#pragma unroll
    for (int nt = 0; nt < 2; ++nt) {
      int c = nstrip + nt * 16 + lrow;
      u16x4 p;
#pragma unroll
      for (int r = 0; r < 4; ++r) p[r] = f2b(fmaxf(acc[mt][nt][r], 0.f));
      *(u16x4*)&dst[obase + (size_t)c * 16384 + w0i] = p;
    }
  }
}

// ---------------- fused QKV: block = (b,h); x1 staged once for Q and K ----------------
__global__ __launch_bounds__(256, 4)
void qkv_kernel(const float* __restrict__ x1, const float* __restrict__ x2,
                const u16* __restrict__ wT,
                u16* __restrict__ q_t, u16* __restrict__ k_t, u16* __restrict__ v_t) {
  __shared__ u16 Xs[128 * LDK];   // x tile [w][c] bf16

  const int t = threadIdx.x;
  const int bh = blockIdx.x;
  const int b = bh >> 7, h = bh & 127;
  const size_t pixbase = (size_t)bh * 16384;
  const size_t obase = (size_t)b * 2097152 + (size_t)h * 128;

  const int lane = t & 63, wave = t >> 6;
  const int lrow = lane & 15, lq = lane >> 4;
  const int nstrip = wave * 32;

  stage_x(Xs, x1, pixbase, t);
  __syncthreads();
  gemm_relu_store(Xs, wT, q_t, obase, lrow, lq, nstrip);
  gemm_relu_store(Xs, wT + 16384, k_t, obase, lrow, lq, nstrip);
  __syncthreads();   // all K-GEMM reads of Xs done
  stage_x(Xs, x2, pixbase, t);
  __syncthreads();
  gemm_relu_store(Xs, wT + 2 * 16384, v_t, obase, lrow, lq, nstrip);
}

// ---------------- attention: per (b,c), S^T = K Q^T, softmax over g, O^T = V^T P^T ----------------
// Q fragments from global regs; Ks: K -> V^T; Ps: P. 3 barriers; direct O store.
__global__ __launch_bounds__(256, 2)
void attn_kernel(u16* __restrict__ q_t, const u16* __restrict__ k_t,
                 const u16* __restrict__ v_t, const float* __restrict__ scale_p) {
  __shared__ u16 Ks[128 * LDK];   // K [g][w] -> V^T [w][g]
  __shared__ u16 Ps[128 * LDK];   // P [h][g]

  const int t = threadIdx.x;
  const size_t base = (size_t)blockIdx.x * 16384;

  const int lane = t & 63, wave = t >> 6;
  const int lrow = lane & 15, lq = lane >> 4;
  const int hstrip = wave * 32;
  const float scl = scale_p[0];

  // Q fragments (per-wave-private rows) straight from global
  bf16x8 q0[4], q1[4];
#pragma unroll
  for (int kk = 0; kk < 4; ++kk) {
    int ko = kk * 32 + lq * 8;
    q0[kk] = *(const bf16x8*)&q_t[base + (hstrip + lrow) * 128 + ko];
    q1[kk] = *(const bf16x8*)&q_t[base + (hstrip + 16 + lrow) * 128 + ko];
  }
  // V into regs (transposed later); K into LDS
  const int g0 = (t & 15) * 8, w0v = (t >> 4) * 8;
  u16x8 vv[8];
#pragma unroll
  for (int i = 0; i < 8; ++i)
    vv[i] = *(const u16x8*)&v_t[base + (g0 + i) * 128 + w0v];
#pragma unroll
  for (int j = 0; j < 8; ++j) {
    int lin = j * 256 + t;
    int r = lin >> 4, c0 = (lin & 15) << 3;
    *(u16x8*)&Ks[r * LDK + c0] = *(const u16x8*)&k_t[base + lin * 8];
  }
  __syncthreads();

  // S^T[g][h]: A = Ks rows g, B = Q frags
  f32x4 acc[8][2];
#pragma unroll
  for (int mt = 0; mt < 8; ++mt) {
    acc[mt][0] = (f32x4){0.f, 0.f, 0.f, 0.f};
    acc[mt][1] = (f32x4){0.f, 0.f, 0.f, 0.f};
  }
#pragma unroll
  for (int kk = 0; kk < 4; ++kk) {
    int ko = kk * 32 + lq * 8;
#pragma unroll
    for (int mt = 0; mt < 8; ++mt) {
      bf16x8 a = *(const bf16x8*)&Ks[(mt * 16 + lrow) * LDK + ko];
      acc[mt][0] = MFMA(a, q0[kk], acc[mt][0]);
      acc[mt][1] = MFMA(a, q1[kk], acc[mt][1]);
    }
  }

  // softmax over g (rows of S^T): per-lane 32 values + quad combine via shfl_xor 16/32
  float inv[2];
#pragma unroll
  for (int nt = 0; nt < 2; ++nt) {
    float mx = -1e30f;
#pragma unroll
    for (int mt = 0; mt < 8; ++mt)
#pragma unroll
      for (int r = 0; r < 4; ++r) {
        acc[mt][nt][r] *= scl;
        mx = fmaxf(mx, acc[mt][nt][r]);
      }
    mx = fmaxf(mx, __shfl_xor(mx, 16));
    mx = fmaxf(mx, __shfl_xor(mx, 32));
    float s = 0.f;
#pragma unroll
    for (int mt = 0; mt < 8; ++mt)
#pragma unroll
      for (int r = 0; r < 4; ++r) {
        float e = __expf(acc[mt][nt][r] - mx);
        acc[mt][nt][r] = e;
        s += e;
      }
    s += __shfl_xor(s, 16);
    s += __shfl_xor(s, 32);
    inv[nt] = 1.f / s;
  }
  __syncthreads();   // all S-MFMA reads of Ks complete -> K dead

  // V^T into Ks (register 8x8 transpose); P into Ps [h][g]
#pragma unroll
  for (int j = 0; j < 8; ++j) {
    u16x8 tv;
#pragma unroll
    for (int i = 0; i < 8; ++i) tv[i] = vv[i][j];
    *(u16x8*)&Ks[(w0v + j) * LDK + g0] = tv;
  }
#pragma unroll
  for (int mt = 0; mt < 8; ++mt) {
    int gg0 = mt * 16 + lq * 4;
#pragma unroll
    for (int nt = 0; nt < 2; ++nt) {
      int hh = hstrip + nt * 16 + lrow;
      u16x4 p;
#pragma unroll
      for (int r = 0; r < 4; ++r) p[r] = f2b(acc[mt][nt][r] * inv[nt]);
      *(u16x4*)&Ps[hh * LDK + gg0] = p;
    }
  }
  __syncthreads();

  // O^T[w][h]: A = Ks(V^T) rows w, B = P rows h; direct store into q_t (own block region)
#pragma unroll
  for (int kk = 0; kk < 4; ++kk) {
    int ko = kk * 32 + lq * 8;
    bf16x8 b0 = *(const bf16x8*)&Ps[(hstrip + lrow) * LDK + ko];
    bf16x8 b1 = *(const bf16x8*)&Ps[(hstrip + 16 + lrow) * LDK + ko];
    if (kk == 0) {
#pragma unroll
      for (int mt = 0; mt < 8; ++mt) {
        acc[mt][0] = (f32x4){0.f, 0.f, 0.f, 0.f};
        acc[mt][1] = (f32x4){0.f, 0.f, 0.f, 0.f};
      }
    }
#pragma unroll
    for (int mt = 0; mt < 8; ++mt) {
      bf16x8 a = *(const bf16x8*)&Ks[(mt * 16 + lrow) * LDK + ko];
      acc[mt][0] = MFMA(a, b0, acc[mt][0]);
      acc[mt][1] = MFMA(a, b1, acc[mt][1]);
    }
  }
#pragma unroll
  for (int mt = 0; mt < 8; ++mt) {
    int w0i = mt * 16 + lq * 4;
#pragma unroll
    for (int nt = 0; nt < 2; ++nt) {
      int hh = hstrip + nt * 16 + lrow;
      u16x4 p;
#pragma unroll
      for (int r = 0; r < 4; ++r) p[r] = f2b(acc[mt][nt][r]);
      *(u16x4*)&q_t[base + hh * 128 + w0i] = p;
    }
  }
}

// ---------------- final: s = o @ Ws + bs; sigmoid; BN; out = x1 + x2*g (fp32) ----------------
// Fused epilogue: residual computed directly in acc layout (lane holds 4 consecutive d
// at fixed w -> 16B coalesced f32x4 loads/stores). 1 barrier, no g' LDS round trip.
__global__ __launch_bounds__(256, 4)
void final_kernel(const u16* __restrict__ o_t, const u16* __restrict__ wsT,
                  const float* __restrict__ x1, const float* __restrict__ x2,
                  const float* __restrict__ bs, const float* __restrict__ gamma,
                  const float* __restrict__ beta, const float* __restrict__ mu,
                  const float* __restrict__ var, float* __restrict__ out) {
  __shared__ u16 Os[128 * LDK];   // o^T tile [w][c]
  __shared__ float bnA[128], bnB[128], bsf[128];

  const int t = threadIdx.x;
  const int bh = blockIdx.x;
  const int b = bh >> 7, h = bh & 127;
  const size_t obase = (size_t)b * 2097152 + (size_t)h * 128;
  const size_t pixbase = (size_t)bh * 16384;

  if (t < 128) {
    float a = gamma[t] * rsqrtf(var[t] + 1e-3f);
    bnA[t] = a;
    bnB[t] = beta[t] - mu[t] * a;
    bsf[t] = bs[t];
  }
  {  // transpose-load o tile -> Os[w][c]
    int c0 = (t & 15) * 8, w0 = (t >> 4) * 8;
    u16 ov[8][8];
#pragma unroll
    for (int i = 0; i < 8; ++i)
      *(u16x8*)&ov[i][0] = *(const u16x8*)&o_t[obase + (size_t)(c0 + i) * 16384 + w0];
#pragma unroll
    for (int j = 0; j < 8; ++j) {
      u16x8 tv;
#pragma unroll
      for (int i = 0; i < 8; ++i) tv[i] = ov[i][j];
      *(u16x8*)&Os[(w0 + j) * LDK + c0] = tv;
    }
  }
  __syncthreads();

  const int lane = t & 63, wave = t >> 6;
  const int lrow = lane & 15, lq = lane >> 4;
  const int wstrip = wave * 32;

  // D[d][w] = sum_c WsT[d][c] * Os[w][c]; A fragments straight from global (L2-hot)
  f32x4 acc[8][2];
#pragma unroll
  for (int mt = 0; mt < 8; ++mt) {
    acc[mt][0] = (f32x4){0.f, 0.f, 0.f, 0.f};
    acc[mt][1] = (f32x4){0.f, 0.f, 0.f, 0.f};
  }
#pragma unroll
  for (int kk = 0; kk < 4; ++kk) {
    int ko = kk * 32 + lq * 8;
    bf16x8 b0 = *(const bf16x8*)&Os[(wstrip + lrow) * LDK + ko];
    bf16x8 b1 = *(const bf16x8*)&Os[(wstrip + 16 + lrow) * LDK + ko];
#pragma unroll
    for (int mt = 0; mt < 8; ++mt) {
      bf16x8 a = *(const bf16x8*)&wsT[(mt * 16 + lrow) * 128 + ko];
      acc[mt][0] = MFMA(a, b0, acc[mt][0]);
      acc[mt][1] = MFMA(a, b1, acc[mt][1]);
    }
  }

  // fused epilogue: sigmoid + BN + gated residual, direct coalesced f32x4 I/O
#pragma unroll
  for (int mt = 0; mt < 8; ++mt) {
    int d0 = mt * 16 + lq * 4;
    f32x4 A4 = *(const f32x4*)&bnA[d0];
    f32x4 B4 = *(const f32x4*)&bnB[d0];
    f32x4 S4 = *(const f32x4*)&bsf[d0];
#pragma unroll
    for (int nt = 0; nt < 2; ++nt) {
      int w = wstrip + nt * 16 + lrow;
      size_t off = pixbase + (size_t)w * 128 + d0;
      f32x4 a1v = *(const f32x4*)&x1[off];
      f32x4 a2v = *(const f32x4*)&x2[off];
      f32x4 r;
#pragma unroll
      for (int r4 = 0; r4 < 4; ++r4) {
        float sv = acc[mt][nt][r4] + S4[r4];
        float sg = 1.f / (1.f + __expf(-sv));
        float g = A4[r4] * sg + B4[r4];
        r[r4] = a1v[r4] + a2v[r4] * g;
      }
      *(f32x4*)&out[off] = r;
    }
  }
}

extern "C" void kernel_launch(void* const* d_in, const int* in_sizes, int n_in,
                              void* d_out, int out_size, void* d_ws, size_t ws_size,
                              hipStream_t stream) {
  const float* x1 = (const float*)d_in[0];
  const float* x2 = (const float*)d_in[1];
  const float* Wq = (const float*)d_in[2];
  const float* Wk = (const float*)d_in[3];
  const float* Wv = (const float*)d_in[4];
  const float* Ws = (const float*)d_in[5];
  const float* bs = (const float*)d_in[6];
  const float* scale = (const float*)d_in[7];
  const float* gamma = (const float*)d_in[8];
  const float* beta = (const float*)d_in[9];
  const float* mu = (const float*)d_in[10];
  const float* var = (const float*)d_in[11];
  float* outp = (float*)d_out;

  // workspace (bf16 elems): q_t | k_t | v_t : [B][C][H][W], then 4 transposed weights
  u16* q_t = (u16*)d_ws;
  u16* k_t = q_t + 16777216;
  u16* v_t = k_t + 16777216;
  u16* wT = v_t + 16777216;  // 4 * 16384

  wprep<<<dim3(4), dim3(256), 0, stream>>>(Wq, Wk, Wv, Ws, wT);
  qkv_kernel<<<dim3(1024), dim3(256), 0, stream>>>(x1, x2, wT, q_t, k_t, v_t);
  attn_kernel<<<dim3(1024), dim3(256), 0, stream>>>(q_t, k_t, v_t, scale);
  final_kernel<<<dim3(1024), dim3(256), 0, stream>>>(q_t, wT + 3 * 16384, x1, x2, bs,
                                                     gamma, beta, mu, var, outp);
}

// Round 2
// 320.767 us; speedup vs baseline: 1.2891x; 1.2891x over previous
//
#include <hip/hip_runtime.h>

typedef unsigned int u32;
typedef unsigned short u16;
typedef u16 u16x4 __attribute__((ext_vector_type(4)));
typedef u16 u16x8 __attribute__((ext_vector_type(8)));
typedef __bf16 bf16x8 __attribute__((ext_vector_type(8)));
typedef float f32x4 __attribute__((ext_vector_type(4)));

#define LDK 136   // padded LDS leading dim (elems): 16B-aligned rows
#define MFMA(a, b, c) __builtin_amdgcn_mfma_f32_16x16x32_bf16(a, b, c, 0, 0, 0)

__device__ __forceinline__ u16 f2b(float f) {
  u32 u = __builtin_bit_cast(u32, f);
  u = (u + 0x7fffu + ((u >> 16) & 1u)) >> 16;
  return (u16)u;
}
__device__ __forceinline__ float b2f(u16 h) {
  u32 u = ((u32)h) << 16;
  return __builtin_bit_cast(float, u);
}

// ---------------- weight prep: wT[m][d][c] = bf16(W_m[c][d]) ----------------
__global__ void wprep(const float* __restrict__ Wq, const float* __restrict__ Wk,
                      const float* __restrict__ Wv, const float* __restrict__ Ws,
                      u16* __restrict__ wT) {
  const float* srcs[4] = {Wq, Wk, Wv, Ws};
  const float* s = srcs[blockIdx.x];
  u16* d = wT + (size_t)blockIdx.x * 16384;
  for (int idx = threadIdx.x; idx < 16384; idx += 256) {
    int i = idx >> 7, j = idx & 127;   // W[i=c_in][j=c_out]
    d[j * 128 + i] = f2b(s[idx]);
  }
}

// ---------------- QKV: block = (b,h,m); GEMM + ReLU + LDS-bounce coalesced store ----
// 34 KB LDS -> 4 blocks/CU; 3072 blocks for overlap. Store path: acc -> Xs[c][w]
// (Xs dead after GEMM) -> 256B-contiguous row stores (full 128B lines, no partial
// line writeback / write-allocate).
__global__ __launch_bounds__(256, 4)
void qkv_kernel(const float* __restrict__ x1, const float* __restrict__ x2,
                const u16* __restrict__ wT,
                u16* __restrict__ q_t, u16* __restrict__ k_t, u16* __restrict__ v_t) {
  __shared__ u16 Xs[128 * LDK];   // x tile [w][c] bf16; later bounce tile [c][w]

  const int t = threadIdx.x;
  const int bh = blockIdx.x;
  const int m = blockIdx.y;       // 0=q, 1=k, 2=v
  const int b = bh >> 7, h = bh & 127;
  const size_t pixbase = (size_t)bh * 16384;
  const size_t obase = (size_t)b * 2097152 + (size_t)h * 128;

  const float* xin = (m == 2) ? x2 : x1;
  u16* dst = (m == 0) ? q_t : (m == 1) ? k_t : v_t;

  const int lane = t & 63, wave = t >> 6;
  const int lrow = lane & 15, lq = lane >> 4;
  const int nstrip = wave * 32;

  // B fragments straight from global (L2-hot, shared by all blocks) — independent of LDS
  const u16* wb = wT + (size_t)m * 16384;
  bf16x8 w0[4], w1[4];
#pragma unroll
  for (int kk = 0; kk < 4; ++kk) {
    int ko = kk * 32 + lq * 8;
    w0[kk] = *(const bf16x8*)&wb[(nstrip + lrow) * 128 + ko];
    w1[kk] = *(const bf16x8*)&wb[(nstrip + 16 + lrow) * 128 + ko];
  }

  // stage x row-tile -> Xs[w][c] bf16
#pragma unroll
  for (int j = 0; j < 8; ++j) {
    int lin = j * 256 + t;
    int w = lin >> 4, c0 = (lin & 15) << 3;
    f32x4 a0 = *(const f32x4*)&xin[pixbase + lin * 8];
    f32x4 a1 = *(const f32x4*)&xin[pixbase + lin * 8 + 4];
    u16x8 p;
#pragma unroll
    for (int i = 0; i < 4; ++i) { p[i] = f2b(a0[i]); p[4 + i] = f2b(a1[i]); }
    *(u16x8*)&Xs[w * LDK + c0] = p;
  }
  __syncthreads();

  f32x4 acc[8][2];
#pragma unroll
  for (int mt = 0; mt < 8; ++mt) {
    acc[mt][0] = (f32x4){0.f, 0.f, 0.f, 0.f};
    acc[mt][1] = (f32x4){0.f, 0.f, 0.f, 0.f};
  }
#pragma unroll
  for (int kk = 0; kk < 4; ++kk) {
    int ko = kk * 32 + lq * 8;
#pragma unroll
    for (int mt = 0; mt < 8; ++mt) {
      bf16x8 a = *(const bf16x8*)&Xs[(mt * 16 + lrow) * LDK + ko];
      acc[mt][0] = MFMA(a, w0[kk], acc[mt][0]);
      acc[mt][1] = MFMA(a, w1[kk], acc[mt][1]);
    }
  }
  __syncthreads();   // all GEMM reads of Xs done -> reuse as bounce tile

  // bounce: relu(acc) -> Xs[c][w] (lane holds 4 consecutive w at fixed c)
#pragma unroll
  for (int mt = 0; mt < 8; ++mt) {
    int w0i = mt * 16 + lq * 4;
#pragma unroll
    for (int nt = 0; nt < 2; ++nt) {
      int c = nstrip + nt * 16 + lrow;
      u16x4 p;
#pragma unroll
      for (int r = 0; r < 4; ++r) p[r] = f2b(fmaxf(acc[mt][nt][r], 0.f));
      *(u16x4*)&Xs[c * LDK + w0i] = p;
    }
  }
  __syncthreads();

  // coalesced store: per j, 16 full c-rows (256B contiguous each)
#pragma unroll
  for (int j = 0; j < 8; ++j) {
    int c = j * 16 + (t >> 4), wv = (t & 15) * 8;
    *(u16x8*)&dst[obase + (size_t)c * 16384 + wv] = *(const u16x8*)&Xs[c * LDK + wv];
  }
}

// ---------------- attention: per (b,c), S^T = K Q^T, softmax over g, O^T = V^T P^T ----------------
// Q fragments from global regs; Ks: K -> V^T -> O bounce; Ps: P. Direct coalesced O store.
__global__ __launch_bounds__(256, 2)
void attn_kernel(u16* __restrict__ q_t, const u16* __restrict__ k_t,
                 const u16* __restrict__ v_t, const float* __restrict__ scale_p) {
  __shared__ u16 Ks[128 * LDK];   // K [g][w] -> V^T [w][g] -> O bounce [h][w]
  __shared__ u16 Ps[128 * LDK];   // P [h][g]

  const int t = threadIdx.x;
  const size_t base = (size_t)blockIdx.x * 16384;

  const int lane = t & 63, wave = t >> 6;
  const int lrow = lane & 15, lq = lane >> 4;
  const int hstrip = wave * 32;
  const float scl = scale_p[0];

  // Q fragments (per-wave-private rows) straight from global
  bf16x8 q0[4], q1[4];
#pragma unroll
  for (int kk = 0; kk < 4; ++kk) {
    int ko = kk * 32 + lq * 8;
    q0[kk] = *(const bf16x8*)&q_t[base + (hstrip + lrow) * 128 + ko];
    q1[kk] = *(const bf16x8*)&q_t[base + (hstrip + 16 + lrow) * 128 + ko];
  }
  // V into regs (transposed later); K into LDS
  const int g0 = (t & 15) * 8, w0v = (t >> 4) * 8;
  u16x8 vv[8];
#pragma unroll
  for (int i = 0; i < 8; ++i)
    vv[i] = *(const u16x8*)&v_t[base + (g0 + i) * 128 + w0v];
#pragma unroll
  for (int j = 0; j < 8; ++j) {
    int lin = j * 256 + t;
    int r = lin >> 4, c0 = (lin & 15) << 3;
    *(u16x8*)&Ks[r * LDK + c0] = *(const u16x8*)&k_t[base + lin * 8];
  }
  __syncthreads();

  // S^T[g][h]: A = Ks rows g, B = Q frags
  f32x4 acc[8][2];
#pragma unroll
  for (int mt = 0; mt < 8; ++mt) {
    acc[mt][0] = (f32x4){0.f, 0.f, 0.f, 0.f};
    acc[mt][1] = (f32x4){0.f, 0.f, 0.f, 0.f};
  }
#pragma unroll
  for (int kk = 0; kk < 4; ++kk) {
    int ko = kk * 32 + lq * 8;
#pragma unroll
    for (int mt = 0; mt < 8; ++mt) {
      bf16x8 a = *(const bf16x8*)&Ks[(mt * 16 + lrow) * LDK + ko];
      acc[mt][0] = MFMA(a, q0[kk], acc[mt][0]);
      acc[mt][1] = MFMA(a, q1[kk], acc[mt][1]);
    }
  }

  // softmax over g (rows of S^T): per-lane 32 values + quad combine via shfl_xor 16/32
  float inv[2];
#pragma unroll
  for (int nt = 0; nt < 2; ++nt) {
    float mx = -1e30f;
#pragma unroll
    for (int mt = 0; mt < 8; ++mt)
#pragma unroll
      for (int r = 0; r < 4; ++r) {
        acc[mt][nt][r] *= scl;
        mx = fmaxf(mx, acc[mt][nt][r]);
      }
    mx = fmaxf(mx, __shfl_xor(mx, 16));
    mx = fmaxf(mx, __shfl_xor(mx, 32));
    float s = 0.f;
#pragma unroll
    for (int mt = 0; mt < 8; ++mt)
#pragma unroll
      for (int r = 0; r < 4; ++r) {
        float e = __expf(acc[mt][nt][r] - mx);
        acc[mt][nt][r] = e;
        s += e;
      }
    s += __shfl_xor(s, 16);
    s += __shfl_xor(s, 32);
    inv[nt] = 1.f / s;
  }
  __syncthreads();   // all S-MFMA reads of Ks complete -> K dead

  // V^T into Ks (register 8x8 transpose); P into Ps [h][g]
#pragma unroll
  for (int j = 0; j < 8; ++j) {
    u16x8 tv;
#pragma unroll
    for (int i = 0; i < 8; ++i) tv[i] = vv[i][j];
    *(u16x8*)&Ks[(w0v + j) * LDK + g0] = tv;
  }
#pragma unroll
  for (int mt = 0; mt < 8; ++mt) {
    int gg0 = mt * 16 + lq * 4;
#pragma unroll
    for (int nt = 0; nt < 2; ++nt) {
      int hh = hstrip + nt * 16 + lrow;
      u16x4 p;
#pragma unroll
      for (int r = 0; r < 4; ++r) p[r] = f2b(acc[mt][nt][r] * inv[nt]);
      *(u16x4*)&Ps[hh * LDK + gg0] = p;
    }
  }
  __syncthreads();

  // O^T[w][h]: A = Ks(V^T) rows w, B = P rows h
#pragma unroll
  for (int kk = 0; kk < 4; ++kk) {
    int ko = kk * 32 + lq * 8;
    bf16x8 b0 = *(const bf16x8*)&Ps[(hstrip + lrow) * LDK + ko];
    bf16x8 b1 = *(const bf16x8*)&Ps[(hstrip + 16 + lrow) * LDK + ko];
    if (kk == 0) {
#pragma unroll
      for (int mt = 0; mt < 8; ++mt) {
        acc[mt][0] = (f32x4){0.f, 0.f, 0.f, 0.f};
        acc[mt][1] = (f32x4){0.f, 0.f, 0.f, 0.f};
      }
    }
#pragma unroll
    for (int mt = 0; mt < 8; ++mt) {
      bf16x8 a = *(const bf16x8*)&Ks[(mt * 16 + lrow) * LDK + ko];
      acc[mt][0] = MFMA(a, b0, acc[mt][0]);
      acc[mt][1] = MFMA(a, b1, acc[mt][1]);
    }
  }
  __syncthreads();   // PV reads of Ks done -> reuse as O bounce tile

  // bounce O -> Ks[h][w], then fully-contiguous 32KB store
#pragma unroll
  for (int mt = 0; mt < 8; ++mt) {
    int w0i = mt * 16 + lq * 4;
#pragma unroll
    for (int nt = 0; nt < 2; ++nt) {
      int hh = hstrip + nt * 16 + lrow;
      u16x4 p;
#pragma unroll
      for (int r = 0; r < 4; ++r) p[r] = f2b(acc[mt][nt][r]);
      *(u16x4*)&Ks[hh * LDK + w0i] = p;
    }
  }
  __syncthreads();
#pragma unroll
  for (int j = 0; j < 8; ++j) {
    int hh = j * 16 + (t >> 4), wv = (t & 15) * 8;
    *(u16x8*)&q_t[base + hh * 128 + wv] = *(const u16x8*)&Ks[hh * LDK + wv];
  }
}

// ---------------- final: s = o @ Ws + bs; sigmoid; BN; out = x1 + x2*g (fp32) ----------------
// Fused epilogue: residual computed directly in acc layout (lane holds 4 consecutive d
// at fixed w -> 16B coalesced f32x4 loads/stores). 1 barrier, no g' LDS round trip.
__global__ __launch_bounds__(256, 4)
void final_kernel(const u16* __restrict__ o_t, const u16* __restrict__ wsT,
                  const float* __restrict__ x1, const float* __restrict__ x2,
                  const float* __restrict__ bs, const float* __restrict__ gamma,
                  const float* __restrict__ beta, const float* __restrict__ mu,
                  const float* __restrict__ var, float* __restrict__ out) {
  __shared__ u16 Os[128 * LDK];   // o^T tile [w][c]
  __shared__ float bnA[128], bnB[128], bsf[128];

  const int t = threadIdx.x;
  const int bh = blockIdx.x;
  const int b = bh >> 7, h = bh & 127;
  const size_t obase = (size_t)b * 2097152 + (size_t)h * 128;
  const size_t pixbase = (size_t)bh * 16384;

  if (t < 128) {
    float a = gamma[t] * rsqrtf(var[t] + 1e-3f);
    bnA[t] = a;
    bnB[t] = beta[t] - mu[t] * a;
    bsf[t] = bs[t];
  }
  {  // transpose-load o tile -> Os[w][c]
    int c0 = (t & 15) * 8, w0 = (t >> 4) * 8;
    u16 ov[8][8];
#pragma unroll
    for (int i = 0; i < 8; ++i)
      *(u16x8*)&ov[i][0] = *(const u16x8*)&o_t[obase + (size_t)(c0 + i) * 16384 + w0];
#pragma unroll
    for (int j = 0; j < 8; ++j) {
      u16x8 tv;
#pragma unroll
      for (int i = 0; i < 8; ++i) tv[i] = ov[i][j];
      *(u16x8*)&Os[(w0 + j) * LDK + c0] = tv;
    }
  }
  __syncthreads();

  const int lane = t & 63, wave = t >> 6;
  const int lrow = lane & 15, lq = lane >> 4;
  const int wstrip = wave * 32;

  // D[d][w] = sum_c WsT[d][c] * Os[w][c]; A fragments straight from global (L2-hot)
  f32x4 acc[8][2];
#pragma unroll
  for (int mt = 0; mt < 8; ++mt) {
    acc[mt][0] = (f32x4){0.f, 0.f, 0.f, 0.f};
    acc[mt][1] = (f32x4){0.f, 0.f, 0.f, 0.f};
  }
#pragma unroll
  for (int kk = 0; kk < 4; ++kk) {
    int ko = kk * 32 + lq * 8;
    bf16x8 b0 = *(const bf16x8*)&Os[(wstrip + lrow) * LDK + ko];
    bf16x8 b1 = *(const bf16x8*)&Os[(wstrip + 16 + lrow) * LDK + ko];
#pragma unroll
    for (int mt = 0; mt < 8; ++mt) {
      bf16x8 a = *(const bf16x8*)&wsT[(mt * 16 + lrow) * 128 + ko];
      acc[mt][0] = MFMA(a, b0, acc[mt][0]);
      acc[mt][1] = MFMA(a, b1, acc[mt][1]);
    }
  }

  // fused epilogue: sigmoid + BN + gated residual, direct coalesced f32x4 I/O
#pragma unroll
  for (int mt = 0; mt < 8; ++mt) {
    int d0 = mt * 16 + lq * 4;
    f32x4 A4 = *(const f32x4*)&bnA[d0];
    f32x4 B4 = *(const f32x4*)&bnB[d0];
    f32x4 S4 = *(const f32x4*)&bsf[d0];
#pragma unroll
    for (int nt = 0; nt < 2; ++nt) {
      int w = wstrip + nt * 16 + lrow;
      size_t off = pixbase + (size_t)w * 128 + d0;
      f32x4 a1v = *(const f32x4*)&x1[off];
      f32x4 a2v = *(const f32x4*)&x2[off];
      f32x4 r;
#pragma unroll
      for (int r4 = 0; r4 < 4; ++r4) {
        float sv = acc[mt][nt][r4] + S4[r4];
        float sg = 1.f / (1.f + __expf(-sv));
        float g = A4[r4] * sg + B4[r4];
        r[r4] = a1v[r4] + a2v[r4] * g;
      }
      *(f32x4*)&out[off] = r;
    }
  }
}

extern "C" void kernel_launch(void* const* d_in, const int* in_sizes, int n_in,
                              void* d_out, int out_size, void* d_ws, size_t ws_size,
                              hipStream_t stream) {
  const float* x1 = (const float*)d_in[0];
  const float* x2 = (const float*)d_in[1];
  const float* Wq = (const float*)d_in[2];
  const float* Wk = (const float*)d_in[3];
  const float* Wv = (const float*)d_in[4];
  const float* Ws = (const float*)d_in[5];
  const float* bs = (const float*)d_in[6];
  const float* scale = (const float*)d_in[7];
  const float* gamma = (const float*)d_in[8];
  const float* beta = (const float*)d_in[9];
  const float* mu = (const float*)d_in[10];
  const float* var = (const float*)d_in[11];
  float* outp = (float*)d_out;

  // workspace (bf16 elems): q_t | k_t | v_t : [B][C][H][W], then 4 transposed weights
  u16* q_t = (u16*)d_ws;
  u16* k_t = q_t + 16777216;
  u16* v_t = k_t + 16777216;
  u16* wT = v_t + 16777216;  // 4 * 16384

  wprep<<<dim3(4), dim3(256), 0, stream>>>(Wq, Wk, Wv, Ws, wT);
  qkv_kernel<<<dim3(1024, 3), dim3(256), 0, stream>>>(x1, x2, wT, q_t, k_t, v_t);
  attn_kernel<<<dim3(1024), dim3(256), 0, stream>>>(q_t, k_t, v_t, scale);
  final_kernel<<<dim3(1024), dim3(256), 0, stream>>>(q_t, wT + 3 * 16384, x1, x2, bs,
                                                     gamma, beta, mu, var, outp);
}